// Round 1
// baseline (1232.617 us; speedup 1.0000x reference)
//
#include <hip/hip_runtime.h>

typedef __bf16 bf16x8 __attribute__((ext_vector_type(8)));
typedef float f32x4 __attribute__((ext_vector_type(4)));

static __device__ __forceinline__ unsigned short f2bf(float f) {
    unsigned u = __builtin_bit_cast(unsigned, f);
    unsigned r = u + 0x7fffu + ((u >> 16) & 1u);   // RNE; inputs finite
    return (unsigned short)(r >> 16);
}

// ---------------- prep: fp32->bf16 weight converts, embedding gather, zeros ----
__global__ __launch_bounds__(256) void k_prep(
    const float* Wih, const float* Whh, const float* Wh, const float* Wc,
    const float* Wout, const float* emb, const int* targets,
    unsigned short* Wih_b, unsigned short* Whh_b, unsigned short* Wh_b,
    unsigned short* Wc_b, unsigned short* Wout_b, unsigned short* Aemb,
    float* out, int* ctrs)
{
    const long N0 = 1048576, N1 = 1048576, N2 = 1048576, N3 = 1048576;
    const long N4 = 5120000, N5 = 2064384, N6 = 640000, N7 = 256;
    const long total = N0 + N1 + N2 + N3 + N4 + N5 + N6 + N7;
    const long stride = (long)gridDim.x * blockDim.x;
    for (long i = (long)blockIdx.x * blockDim.x + threadIdx.x; i < total; i += stride) {
        long j = i;
        if (j < N0) { Wih_b[j] = f2bf(Wih[j]); continue; } j -= N0;
        if (j < N1) { Whh_b[j] = f2bf(Whh[j]); continue; } j -= N1;
        if (j < N2) { Wh_b[j]  = f2bf(Wh[j]);  continue; } j -= N2;
        if (j < N3) { Wc_b[j]  = f2bf(Wc[j]);  continue; } j -= N3;
        if (j < N4) { Wout_b[j] = f2bf(Wout[j]); continue; } j -= N4;
        if (j < N5) {  // gathered embeddings: row m = b*63+t -> targets[b*64+t]
            long m = j >> 9; int k = (int)(j & 511);
            int b = (int)(m / 63), t = (int)(m - (long)b * 63);
            int row = targets[b * 64 + t];
            Aemb[j] = f2bf(emb[(long)row * 512 + k]);
            continue;
        } j -= N5;
        if (j < N6) {  // zero d_out[:, 0, :]
            long b = j / 10000, v = j - b * 10000;
            out[b * 640000 + v] = 0.f;
            continue;
        } j -= N6;
        ctrs[j] = 0;
    }
}

// ---------------- mean over P=196, store bf16 [64][2048] ----------------------
__global__ __launch_bounds__(256) void k_mean(const float* enc, unsigned short* mean_b)
{
    int b = blockIdx.x;
    int c0 = threadIdx.x * 8;
    float s[8];
#pragma unroll
    for (int k = 0; k < 8; k++) s[k] = 0.f;
    const float* base = enc + (long)b * 196 * 2048 + c0;
    for (int p = 0; p < 196; p++) {
        const float4* q = (const float4*)(base + (long)p * 2048);
        float4 v0 = q[0], v1 = q[1];
        s[0] += v0.x; s[1] += v0.y; s[2] += v0.z; s[3] += v0.w;
        s[4] += v1.x; s[5] += v1.y; s[6] += v1.z; s[7] += v1.w;
    }
    unsigned short r[8];
#pragma unroll
    for (int k = 0; k < 8; k++) r[k] = f2bf(s[k] * (1.f / 196.f));
    uint4 u;
    u.x = (unsigned)r[0] | ((unsigned)r[1] << 16);
    u.y = (unsigned)r[2] | ((unsigned)r[3] << 16);
    u.z = (unsigned)r[4] | ((unsigned)r[5] << 16);
    u.w = (unsigned)r[6] | ((unsigned)r[7] << 16);
    *(uint4*)(mean_b + (long)b * 2048 + c0) = u;
}

// ---------------- h0/c0: [64x2048] @ [1024x2048]^T, tanh epilogue -------------
__global__ __launch_bounds__(256) void k_h0c0(
    const unsigned short* A, const unsigned short* Whb, const unsigned short* Wcb,
    const float* bh, const float* bc, unsigned short* Hbuf, float* c0buf)
{
    __shared__ unsigned short As[64 * 40];
    __shared__ unsigned short Bs[64 * 40];
    const int tid = threadIdx.x;
    const int n0 = blockIdx.x * 64;
    const int w = tid >> 6, lane = tid & 63, quad = lane >> 4, l16 = lane & 15;
    const int r = tid >> 2, seg = tid & 3;
    f32x4 acc[4];
#pragma unroll
    for (int i = 0; i < 4; i++) acc[i] = (f32x4){0.f, 0.f, 0.f, 0.f};

    for (int kb = 0; kb < 64; kb++) {
        int k0 = kb * 32;
        *(uint4*)&As[r * 40 + seg * 8] = *(const uint4*)&A[(long)r * 2048 + k0 + seg * 8];
        int ngr = n0 + r;
        const unsigned short* bsrc = (ngr < 512) ? (Whb + (long)ngr * 2048)
                                                 : (Wcb + (long)(ngr - 512) * 2048);
        *(uint4*)&Bs[r * 40 + seg * 8] = *(const uint4*)&bsrc[k0 + seg * 8];
        __syncthreads();
        bf16x8 bfr = *(const bf16x8*)&Bs[(16 * w + l16) * 40 + quad * 8];
#pragma unroll
        for (int mt = 0; mt < 4; mt++) {
            bf16x8 af = *(const bf16x8*)&As[(mt * 16 + l16) * 40 + quad * 8];
            acc[mt] = __builtin_amdgcn_mfma_f32_16x16x32_bf16(af, bfr, acc[mt], 0, 0, 0);
        }
        __syncthreads();
    }
    int ng = n0 + 16 * w + l16;
    int j = ng & 511;
    float bias = (ng < 512) ? bh[j] : bc[j];
#pragma unroll
    for (int mt = 0; mt < 4; mt++) {
#pragma unroll
        for (int rr = 0; rr < 4; rr++) {
            int m = mt * 16 + quad * 4 + rr;
            float v = tanhf(acc[mt][rr] + bias);
            if (ng < 512) Hbuf[(long)m * 512 + j] = f2bf(v);
            else          c0buf[(long)m * 512 + j] = v;
        }
    }
}

// ---------------- xg: [4032x512] @ [2048x512]^T + biases, fp32 out ------------
__global__ __launch_bounds__(256) void k_xg(
    const unsigned short* A, const unsigned short* Bw,
    const float* bih, const float* bhh, float* xg)
{
    __shared__ unsigned short As[64 * 40];
    __shared__ unsigned short Bs[64 * 40];
    const int tid = threadIdx.x;
    const int n0 = blockIdx.x * 64, m0 = blockIdx.y * 64;
    const int w = tid >> 6, lane = tid & 63, quad = lane >> 4, l16 = lane & 15;
    const int r = tid >> 2, seg = tid & 3;
    f32x4 acc[4];
#pragma unroll
    for (int i = 0; i < 4; i++) acc[i] = (f32x4){0.f, 0.f, 0.f, 0.f};

    for (int kb = 0; kb < 16; kb++) {
        int k0 = kb * 32;
        *(uint4*)&As[r * 40 + seg * 8] = *(const uint4*)&A[(long)(m0 + r) * 512 + k0 + seg * 8];
        *(uint4*)&Bs[r * 40 + seg * 8] = *(const uint4*)&Bw[(long)(n0 + r) * 512 + k0 + seg * 8];
        __syncthreads();
        bf16x8 bfr = *(const bf16x8*)&Bs[(16 * w + l16) * 40 + quad * 8];
#pragma unroll
        for (int mt = 0; mt < 4; mt++) {
            bf16x8 af = *(const bf16x8*)&As[(mt * 16 + l16) * 40 + quad * 8];
            acc[mt] = __builtin_amdgcn_mfma_f32_16x16x32_bf16(af, bfr, acc[mt], 0, 0, 0);
        }
        __syncthreads();
    }
    int ng = n0 + 16 * w + l16;
    float bias = bih[ng] + bhh[ng];
#pragma unroll
    for (int mt = 0; mt < 4; mt++) {
#pragma unroll
        for (int rr = 0; rr < 4; rr++) {
            int m = m0 + mt * 16 + quad * 4 + rr;
            xg[(long)m * 2048 + ng] = acc[mt][rr] + bias;
        }
    }
}

// ---------------- scan: 64 blocks = 4 batch-slices x 16 hidden-slices ---------
__global__ __launch_bounds__(256, 1) void k_scan(
    const unsigned short* Whh_b, const float* xg, const float* c0buf,
    unsigned short* Hbuf, int* ctrs)
{
    __shared__ unsigned short Wlds[128 * 520];  // 133 KB, stride 520 -> 2-way (free)
    __shared__ float gs[16 * 132];              // gate exchange
    const int tid = threadIdx.x;
    const int gid = blockIdx.x;
    const int b0 = (gid & 3) * 16;   // batch slice
    const int j0 = (gid >> 2) * 32;  // hidden-unit slice
    const int w = tid >> 6, lane = tid & 63, quad = lane >> 4, l16 = lane & 15;

    // resident W_hh slice: rows n_rel = q*32+u  <->  W_hh row q*512 + j0 + u
    for (int nrel = w; nrel < 128; nrel += 4) {
        int q = nrel >> 5, u = nrel & 31;
        *(uint4*)&Wlds[nrel * 520 + lane * 8] =
            *(const uint4*)&Whh_b[(long)(q * 512 + j0 + u) * 512 + lane * 8];
    }
    float creg[2];
#pragma unroll
    for (int e = 0; e < 2; e++) {
        int pp = tid + e * 256; int m = pp >> 5, u = pp & 31;
        creg[e] = c0buf[(long)(b0 + m) * 512 + j0 + u];
    }
    __syncthreads();
    int* ctr = ctrs + (gid & 3) * 64;

    for (int s = 1; s < 64; s++) {
        // prefetch xg (independent of h) to hide L3 latency behind MFMA
        float xv[2][4];
#pragma unroll
        for (int e = 0; e < 2; e++) {
            int pp = tid + e * 256; int m = pp >> 5, u = pp & 31;
            const float* xb = xg + ((long)(b0 + m) * 63 + (s - 1)) * 2048 + j0 + u;
            xv[e][0] = xb[0]; xv[e][1] = xb[512]; xv[e][2] = xb[1024]; xv[e][3] = xb[1536];
        }
        // prefetch all A fragments (h[s-1], 16 rows x 512) from global
        const unsigned short* hprev = Hbuf + ((long)(s - 1) * 64 + b0 + l16) * 512 + quad * 8;
        uint4 araw[16];
#pragma unroll
        for (int kk = 0; kk < 16; kk++) araw[kk] = *(const uint4*)(hprev + kk * 32);

        f32x4 acc0 = (f32x4){0.f, 0.f, 0.f, 0.f};
        f32x4 acc1 = (f32x4){0.f, 0.f, 0.f, 0.f};
#pragma unroll
        for (int kk = 0; kk < 16; kk++) {
            bf16x8 a = __builtin_bit_cast(bf16x8, araw[kk]);
            bf16x8 bA = *(const bf16x8*)&Wlds[(32 * w + l16) * 520 + kk * 32 + quad * 8];
            bf16x8 bB = *(const bf16x8*)&Wlds[(32 * w + 16 + l16) * 520 + kk * 32 + quad * 8];
            acc0 = __builtin_amdgcn_mfma_f32_16x16x32_bf16(a, bA, acc0, 0, 0, 0);
            acc1 = __builtin_amdgcn_mfma_f32_16x16x32_bf16(a, bB, acc1, 0, 0, 0);
        }
#pragma unroll
        for (int rr = 0; rr < 4; rr++) {
            gs[(quad * 4 + rr) * 132 + 32 * w + l16] = acc0[rr];
            gs[(quad * 4 + rr) * 132 + 32 * w + 16 + l16] = acc1[rr];
        }
        __syncthreads();
#pragma unroll
        for (int e = 0; e < 2; e++) {
            int pp = tid + e * 256; int m = pp >> 5, u = pp & 31;
            float gi = gs[m * 132 + u]       + xv[e][0];
            float gf = gs[m * 132 + 32 + u]  + xv[e][1];
            float gg = gs[m * 132 + 64 + u]  + xv[e][2];
            float go = gs[m * 132 + 96 + u]  + xv[e][3];
            float si = 1.f / (1.f + __expf(-gi));
            float sf = 1.f / (1.f + __expf(-gf));
            float tg = tanhf(gg);
            float so = 1.f / (1.f + __expf(-go));
            float c = sf * creg[e] + si * tg;
            creg[e] = c;
            float h = so * tanhf(c);
            Hbuf[((long)s * 64 + b0 + m) * 512 + j0 + u] = f2bf(h);
        }
        // inter-block barrier among the 16 hidden-slice blocks of this batch group
        __threadfence();
        __syncthreads();
        if (tid == 0) {
            __hip_atomic_fetch_add(ctr, 1, __ATOMIC_RELEASE, __HIP_MEMORY_SCOPE_AGENT);
            while (__hip_atomic_load(ctr, __ATOMIC_ACQUIRE, __HIP_MEMORY_SCOPE_AGENT) < s * 16) {}
        }
        __syncthreads();
        __threadfence();
    }
}

// ---------------- logits: [4032x512] @ [10000x512]^T + bout -> d_out ----------
__global__ __launch_bounds__(256) void k_out(
    const unsigned short* A, const unsigned short* Wob, const float* bout, float* out)
{
    __shared__ unsigned short As[64 * 40];
    __shared__ unsigned short Bs[64 * 40];
    const int tid = threadIdx.x;
    const int n0 = blockIdx.x * 64, m0 = blockIdx.y * 64;
    const int s = blockIdx.y + 1;
    const int w = tid >> 6, lane = tid & 63, quad = lane >> 4, l16 = lane & 15;
    const int r = tid >> 2, seg = tid & 3;
    f32x4 acc[4];
#pragma unroll
    for (int i = 0; i < 4; i++) acc[i] = (f32x4){0.f, 0.f, 0.f, 0.f};

    for (int kb = 0; kb < 16; kb++) {
        int k0 = kb * 32;
        *(uint4*)&As[r * 40 + seg * 8] = *(const uint4*)&A[(long)(m0 + r) * 512 + k0 + seg * 8];
        int ngr = n0 + r;
        uint4 bv; bv.x = 0u; bv.y = 0u; bv.z = 0u; bv.w = 0u;
        if (ngr < 10000) bv = *(const uint4*)&Wob[(long)ngr * 512 + k0 + seg * 8];
        *(uint4*)&Bs[r * 40 + seg * 8] = bv;
        __syncthreads();
        bf16x8 bfr = *(const bf16x8*)&Bs[(16 * w + l16) * 40 + quad * 8];
#pragma unroll
        for (int mt = 0; mt < 4; mt++) {
            bf16x8 af = *(const bf16x8*)&As[(mt * 16 + l16) * 40 + quad * 8];
            acc[mt] = __builtin_amdgcn_mfma_f32_16x16x32_bf16(af, bfr, acc[mt], 0, 0, 0);
        }
        __syncthreads();
    }
    int ng = n0 + 16 * w + l16;
    if (ng < 10000) {
        float bias = bout[ng];
#pragma unroll
        for (int mt = 0; mt < 4; mt++) {
#pragma unroll
            for (int rr = 0; rr < 4; rr++) {
                int b = mt * 16 + quad * 4 + rr;  // batch index within this s
                out[((long)b * 64 + s) * 10000 + ng] = acc[mt][rr] + bias;
            }
        }
    }
}

extern "C" void kernel_launch(void* const* d_in, const int* in_sizes, int n_in,
                              void* d_out, int out_size, void* d_ws, size_t ws_size,
                              hipStream_t stream)
{
    const float* enc     = (const float*)d_in[0];
    const int*   targets = (const int*)d_in[1];
    const float* emb     = (const float*)d_in[2];
    const float* Wih     = (const float*)d_in[3];
    const float* Whh     = (const float*)d_in[4];
    const float* bih     = (const float*)d_in[5];
    const float* bhh     = (const float*)d_in[6];
    const float* Wh      = (const float*)d_in[7];
    const float* bh      = (const float*)d_in[8];
    const float* Wc      = (const float*)d_in[9];
    const float* bc      = (const float*)d_in[10];
    const float* Wout    = (const float*)d_in[11];
    const float* bout    = (const float*)d_in[12];
    float* out = (float*)d_out;

    char* ws = (char*)d_ws;
    size_t off = 0;
    auto alloc = [&](size_t bytes) {
        void* p = ws + off;
        off = (off + bytes + 255) & ~(size_t)255;
        return p;
    };
    unsigned short* mean_b = (unsigned short*)alloc((size_t)64 * 2048 * 2);
    unsigned short* Wih_b  = (unsigned short*)alloc((size_t)2048 * 512 * 2);
    unsigned short* Whh_b  = (unsigned short*)alloc((size_t)2048 * 512 * 2);
    unsigned short* Wh_b   = (unsigned short*)alloc((size_t)512 * 2048 * 2);
    unsigned short* Wc_b   = (unsigned short*)alloc((size_t)512 * 2048 * 2);
    unsigned short* Wout_b = (unsigned short*)alloc((size_t)10000 * 512 * 2);
    unsigned short* Aemb   = (unsigned short*)alloc((size_t)4032 * 512 * 2);
    float*          xg     = (float*)alloc((size_t)4032 * 2048 * 4);
    unsigned short* Hbuf   = (unsigned short*)alloc((size_t)64 * 64 * 512 * 2);
    float*          c0buf  = (float*)alloc((size_t)64 * 512 * 4);
    int*            ctrs   = (int*)alloc(256 * 4);

    k_prep<<<4096, 256, 0, stream>>>(Wih, Whh, Wh, Wc, Wout, emb, targets,
                                     Wih_b, Whh_b, Wh_b, Wc_b, Wout_b, Aemb, out, ctrs);
    k_mean<<<64, 256, 0, stream>>>(enc, mean_b);
    k_h0c0<<<16, 256, 0, stream>>>(mean_b, Wh_b, Wc_b, bh, bc, Hbuf, c0buf);
    k_xg<<<dim3(32, 63), 256, 0, stream>>>(Aemb, Wih_b, bih, bhh, xg);
    k_scan<<<64, 256, 0, stream>>>(Whh_b, xg, c0buf, Hbuf, ctrs);
    k_out<<<dim3(157, 63), 256, 0, stream>>>(Hbuf + 64 * 512, Wout_b, bout, out);
}

// Round 2
// 649.246 us; speedup vs baseline: 1.8985x; 1.8985x over previous
//
#include <hip/hip_runtime.h>

typedef __bf16 bf16x8 __attribute__((ext_vector_type(8)));
typedef float f32x4 __attribute__((ext_vector_type(4)));

static __device__ __forceinline__ unsigned short f2bf(float f) {
    unsigned u = __builtin_bit_cast(unsigned, f);
    unsigned r = u + 0x7fffu + ((u >> 16) & 1u);   // RNE; inputs finite
    return (unsigned short)(r >> 16);
}

#define GLD_LDS16(g, l) __builtin_amdgcn_global_load_lds( \
    (const __attribute__((address_space(1))) unsigned int*)(const void*)(g), \
    (__attribute__((address_space(3))) unsigned int*)(void*)(l), 16, 0, 0)

// ---------------- prep: fp32->bf16 converts, embedding gather, zeros ----------
__global__ __launch_bounds__(256) void k_prep(
    const float* Wih, const float* Whh, const float* Wh, const float* Wc,
    const float* Wout, const float* emb, const int* targets,
    unsigned short* Wih_b, unsigned short* Whh_b, unsigned short* Wh_b,
    unsigned short* Wc_b, unsigned short* Wout_b, unsigned short* Aemb,
    float* out, int* ctrs, float* ps)
{
    const long N0 = 1048576, N1 = 1048576, N2 = 1048576, N3 = 1048576;
    const long N4 = 5120000, N5 = 2064384, N6 = 640000, N7 = 256, N8 = 65536;
    const long total = N0 + N1 + N2 + N3 + N4 + N5 + N6 + N7 + N8;
    const long stride = (long)gridDim.x * blockDim.x;
    for (long i = (long)blockIdx.x * blockDim.x + threadIdx.x; i < total; i += stride) {
        long j = i;
        if (j < N0) { Wih_b[j] = f2bf(Wih[j]); continue; } j -= N0;
        if (j < N1) { Whh_b[j] = f2bf(Whh[j]); continue; } j -= N1;
        if (j < N2) { Wh_b[j]  = f2bf(Wh[j]);  continue; } j -= N2;
        if (j < N3) { Wc_b[j]  = f2bf(Wc[j]);  continue; } j -= N3;
        if (j < N4) { Wout_b[j] = f2bf(Wout[j]); continue; } j -= N4;
        if (j < N5) {  // gathered embeddings: row m = b*63+t -> targets[b*64+t]
            long m = j >> 9; int k = (int)(j & 511);
            int b = (int)(m / 63), t = (int)(m - (long)b * 63);
            int row = targets[b * 64 + t];
            Aemb[j] = f2bf(emb[(long)row * 512 + k]);
            continue;
        } j -= N5;
        if (j < N6) {  // zero d_out[:, 0, :]
            long b = j / 10000, v = j - b * 10000;
            out[b * 640000 + v] = 0.f;
            continue;
        } j -= N6;
        if (j < N7) { ctrs[j] = 0; continue; } j -= N7;
        ps[j] = 0.f;
    }
}

// ---------------- mean over P=196, store bf16 [64][2048] ----------------------
__global__ __launch_bounds__(128) void k_mean(const float* enc, unsigned short* mean_b)
{
    int b = blockIdx.y;
    int c = blockIdx.x * 128 + threadIdx.x;
    const float* base = enc + (long)b * 196 * 2048 + c;
    float s0 = 0.f, s1 = 0.f, s2 = 0.f, s3 = 0.f;
    for (int p = 0; p < 196; p += 4) {
        s0 += base[(long)(p + 0) * 2048];
        s1 += base[(long)(p + 1) * 2048];
        s2 += base[(long)(p + 2) * 2048];
        s3 += base[(long)(p + 3) * 2048];
    }
    mean_b[(long)b * 2048 + c] = f2bf((s0 + s1 + s2 + s3) * (1.f / 196.f));
}

// ---------------- h0/c0 partials: split-K x4, fp32 atomic accumulate ----------
__global__ __launch_bounds__(256) void k_h0c0(
    const unsigned short* A, const unsigned short* Whb, const unsigned short* Wcb,
    float* ps)
{
    __shared__ unsigned short As[64 * 40];
    __shared__ unsigned short Bs[64 * 40];
    const int tid = threadIdx.x;
    const int n0 = blockIdx.x * 64;
    const int kc = blockIdx.y * 16;
    const int w = tid >> 6, lane = tid & 63, quad = lane >> 4, l16 = lane & 15;
    const int r = tid >> 2, seg = tid & 3;
    f32x4 acc[4];
#pragma unroll
    for (int i = 0; i < 4; i++) acc[i] = (f32x4){0.f, 0.f, 0.f, 0.f};

    for (int kb = kc; kb < kc + 16; kb++) {
        int k0 = kb * 32;
        *(uint4*)&As[r * 40 + seg * 8] = *(const uint4*)&A[(long)r * 2048 + k0 + seg * 8];
        int ngr = n0 + r;
        const unsigned short* bsrc = (ngr < 512) ? (Whb + (long)ngr * 2048)
                                                 : (Wcb + (long)(ngr - 512) * 2048);
        *(uint4*)&Bs[r * 40 + seg * 8] = *(const uint4*)&bsrc[k0 + seg * 8];
        __syncthreads();
        bf16x8 bfr = *(const bf16x8*)&Bs[(16 * w + l16) * 40 + quad * 8];
#pragma unroll
        for (int mt = 0; mt < 4; mt++) {
            bf16x8 af = *(const bf16x8*)&As[(mt * 16 + l16) * 40 + quad * 8];
            acc[mt] = __builtin_amdgcn_mfma_f32_16x16x32_bf16(af, bfr, acc[mt], 0, 0, 0);
        }
        __syncthreads();
    }
    int ng = n0 + 16 * w + l16;
#pragma unroll
    for (int mt = 0; mt < 4; mt++) {
#pragma unroll
        for (int rr = 0; rr < 4; rr++) {
            int m = mt * 16 + quad * 4 + rr;
            atomicAdd(&ps[(long)m * 1024 + ng], acc[mt][rr]);
        }
    }
}

// ---------------- h0/c0 finalize: tanh(ps + bias) -> Hbuf[0] / c0buf ----------
__global__ __launch_bounds__(256) void k_fin(
    const float* ps, const float* bh, const float* bc,
    unsigned short* Hbuf, float* c0buf)
{
    int i = blockIdx.x * 256 + threadIdx.x;   // 65536 = 64 x 1024
    int m = i >> 10, ng = i & 1023;
    int j = ng & 511;
    float bias = (ng < 512) ? bh[j] : bc[j];
    float v = tanhf(ps[i] + bias);
    if (ng < 512) Hbuf[(long)m * 512 + j] = f2bf(v);
    else          c0buf[(long)m * 512 + j] = v;
}

// ---------------- xg: [4032x512] @ [2048x512]^T + biases, fp32 out ------------
__global__ __launch_bounds__(256) void k_xg(
    const unsigned short* A, const unsigned short* Bw,
    const float* bih, const float* bhh, float* xg)
{
    __shared__ unsigned short As[64 * 40];
    __shared__ unsigned short Bs[64 * 40];
    const int tid = threadIdx.x;
    const int n0 = blockIdx.x * 64, m0 = blockIdx.y * 64;
    const int w = tid >> 6, lane = tid & 63, quad = lane >> 4, l16 = lane & 15;
    const int r = tid >> 2, seg = tid & 3;
    f32x4 acc[4];
#pragma unroll
    for (int i = 0; i < 4; i++) acc[i] = (f32x4){0.f, 0.f, 0.f, 0.f};

    for (int kb = 0; kb < 16; kb++) {
        int k0 = kb * 32;
        *(uint4*)&As[r * 40 + seg * 8] = *(const uint4*)&A[(long)(m0 + r) * 512 + k0 + seg * 8];
        *(uint4*)&Bs[r * 40 + seg * 8] = *(const uint4*)&Bw[(long)(n0 + r) * 512 + k0 + seg * 8];
        __syncthreads();
        bf16x8 bfr = *(const bf16x8*)&Bs[(16 * w + l16) * 40 + quad * 8];
#pragma unroll
        for (int mt = 0; mt < 4; mt++) {
            bf16x8 af = *(const bf16x8*)&As[(mt * 16 + l16) * 40 + quad * 8];
            acc[mt] = __builtin_amdgcn_mfma_f32_16x16x32_bf16(af, bfr, acc[mt], 0, 0, 0);
        }
        __syncthreads();
    }
    int ng = n0 + 16 * w + l16;
    float bias = bih[ng] + bhh[ng];
#pragma unroll
    for (int mt = 0; mt < 4; mt++) {
#pragma unroll
        for (int rr = 0; rr < 4; rr++) {
            int m = m0 + mt * 16 + quad * 4 + rr;
            xg[(long)m * 2048 + ng] = acc[mt][rr] + bias;
        }
    }
}

// ---------------- scan: 64 blocks = 4 batch-groups x 16 hidden-slices ---------
// Fence-free cross-block exchange: h stored/loaded with relaxed agent-scope
// atomics (write-through to LLC, no L2 invalidate/writeback fences).
__global__ __launch_bounds__(256, 1) void k_scan(
    const unsigned short* Whh_b, const float* xg, const float* c0buf,
    unsigned short* Hbuf, int* ctrs)
{
    __shared__ unsigned short Wlds[128 * 520];  // 130 KB resident W_hh slice
    __shared__ unsigned short hs[16 * 520];     // staged h[s-1] (16 batches x 512)
    __shared__ float gs[16 * 133];              // gate exchange
    const int tid = threadIdx.x;
    const int gid = blockIdx.x;
    const int b0 = (gid & 3) * 16;   // batch group
    const int j0 = (gid >> 2) * 32;  // hidden-unit slice
    const int w = tid >> 6, lane = tid & 63, quad = lane >> 4, l16 = lane & 15;
    const int m = tid >> 4, u0 = (tid & 15) * 2;

    // resident W_hh slice: rows nrel = q*32+u  <->  W_hh row q*512 + j0 + u
    for (int nrel = w; nrel < 128; nrel += 4) {
        int q = nrel >> 5, u = nrel & 31;
        *(uint4*)&Wlds[nrel * 520 + lane * 8] =
            *(const uint4*)&Whh_b[(long)(q * 512 + j0 + u) * 512 + lane * 8];
    }
    float2 cr = *(const float2*)&c0buf[(long)(b0 + m) * 512 + j0 + u0];
    float c0v = cr.x, c1v = cr.y;
    int* ctr = ctrs + (gid & 3) * 64;
    __syncthreads();

    for (int s = 1; s < 64; s++) {
        // xg prefetch (read-only, normal cached loads)
        const float* xb = xg + ((long)(b0 + m) * 63 + (s - 1)) * 2048 + j0 + u0;
        float2 xv0 = *(const float2*)(xb + 0);
        float2 xv1 = *(const float2*)(xb + 512);
        float2 xv2 = *(const float2*)(xb + 1024);
        float2 xv3 = *(const float2*)(xb + 1536);

        // coherent staging of h[s-1]: 16 rows x 256 dwords, round j = row j
        const unsigned* hsrc = (const unsigned*)(Hbuf + ((long)(s - 1) * 64 + b0) * 512);
        unsigned hv[16];
#pragma unroll
        for (int j = 0; j < 16; j++)
            hv[j] = __hip_atomic_load(hsrc + j * 256 + tid, __ATOMIC_RELAXED,
                                      __HIP_MEMORY_SCOPE_AGENT);
#pragma unroll
        for (int j = 0; j < 16; j++)
            *(unsigned*)&hs[j * 520 + tid * 2] = hv[j];
        __syncthreads();

        f32x4 acc0 = (f32x4){0.f, 0.f, 0.f, 0.f};
        f32x4 acc1 = (f32x4){0.f, 0.f, 0.f, 0.f};
#pragma unroll
        for (int kk = 0; kk < 16; kk++) {
            bf16x8 a  = *(const bf16x8*)&hs[l16 * 520 + kk * 32 + quad * 8];
            bf16x8 bA = *(const bf16x8*)&Wlds[(32 * w + l16) * 520 + kk * 32 + quad * 8];
            bf16x8 bB = *(const bf16x8*)&Wlds[(32 * w + 16 + l16) * 520 + kk * 32 + quad * 8];
            acc0 = __builtin_amdgcn_mfma_f32_16x16x32_bf16(a, bA, acc0, 0, 0, 0);
            acc1 = __builtin_amdgcn_mfma_f32_16x16x32_bf16(a, bB, acc1, 0, 0, 0);
        }
#pragma unroll
        for (int rr = 0; rr < 4; rr++) {
            gs[(quad * 4 + rr) * 133 + 32 * w + l16] = acc0[rr];
            gs[(quad * 4 + rr) * 133 + 32 * w + 16 + l16] = acc1[rr];
        }
        __syncthreads();

        float gi0 = gs[m * 133 + u0]          + xv0.x;
        float gi1 = gs[m * 133 + u0 + 1]      + xv0.y;
        float gf0 = gs[m * 133 + 32 + u0]     + xv1.x;
        float gf1 = gs[m * 133 + 33 + u0]     + xv1.y;
        float gg0 = gs[m * 133 + 64 + u0]     + xv2.x;
        float gg1 = gs[m * 133 + 65 + u0]     + xv2.y;
        float go0 = gs[m * 133 + 96 + u0]     + xv3.x;
        float go1 = gs[m * 133 + 97 + u0]     + xv3.y;
        float cn0 = (1.f / (1.f + __expf(-gf0))) * c0v + (1.f / (1.f + __expf(-gi0))) * tanhf(gg0);
        float cn1 = (1.f / (1.f + __expf(-gf1))) * c1v + (1.f / (1.f + __expf(-gi1))) * tanhf(gg1);
        c0v = cn0; c1v = cn1;
        float h0v = (1.f / (1.f + __expf(-go0))) * tanhf(cn0);
        float h1v = (1.f / (1.f + __expf(-go1))) * tanhf(cn1);
        unsigned hp = (unsigned)f2bf(h0v) | ((unsigned)f2bf(h1v) << 16);
        __hip_atomic_store((unsigned*)(Hbuf + ((long)s * 64 + b0 + m) * 512 + j0 + u0), hp,
                           __ATOMIC_RELAXED, __HIP_MEMORY_SCOPE_AGENT);

        if (s < 63) {
            __syncthreads();   // all waves' h stores drained (vmcnt 0) before count
            if (tid == 0) {
                __hip_atomic_fetch_add(ctr, 1, __ATOMIC_RELEASE, __HIP_MEMORY_SCOPE_AGENT);
                int target = s * 16;
                while (__hip_atomic_load(ctr, __ATOMIC_RELAXED, __HIP_MEMORY_SCOPE_AGENT) < target) {}
            }
            __syncthreads();
        }
    }
}

// ---------------- logits: m97-style 128x128 tile, global_load_lds width 16 ----
__global__ __launch_bounds__(256) void k_out(
    const unsigned short* A, const unsigned short* Wob, const float* bout, float* out)
{
    __shared__ unsigned short As[128 * 32];
    __shared__ unsigned short Bs[128 * 32];
    const int tid = threadIdx.x;
    const int n0 = blockIdx.x * 128, m0 = blockIdx.y * 128;
    const int w = tid >> 6, lane = tid & 63, quad = lane >> 4, l16 = lane & 15;
    const int wm = w >> 1, wn = w & 1;
    const int gr = lane >> 2, gc = (lane & 3) * 8;

    f32x4 acc[4][4];
#pragma unroll
    for (int i = 0; i < 4; i++)
#pragma unroll
        for (int j = 0; j < 4; j++) acc[i][j] = (f32x4){0.f, 0.f, 0.f, 0.f};

    for (int kb = 0; kb < 16; kb++) {
        int k0 = kb * 32;
#pragma unroll
        for (int p = 0; p < 2; p++) {
            int rowa = m0 + p * 64 + w * 16 + gr;
            GLD_LDS16(A + (long)rowa * 512 + k0 + gc, As + (p * 64 + w * 16) * 32);
            int rowb = n0 + p * 64 + w * 16 + gr;
            GLD_LDS16(Wob + (long)rowb * 512 + k0 + gc, Bs + (p * 64 + w * 16) * 32);
        }
        __syncthreads();
        bf16x8 af[4], bf[4];
#pragma unroll
        for (int mt = 0; mt < 4; mt++)
            af[mt] = *(const bf16x8*)&As[(wm * 64 + mt * 16 + l16) * 32 + quad * 8];
#pragma unroll
        for (int nt = 0; nt < 4; nt++)
            bf[nt] = *(const bf16x8*)&Bs[(wn * 64 + nt * 16 + l16) * 32 + quad * 8];
#pragma unroll
        for (int mt = 0; mt < 4; mt++)
#pragma unroll
            for (int nt = 0; nt < 4; nt++)
                acc[mt][nt] = __builtin_amdgcn_mfma_f32_16x16x32_bf16(af[mt], bf[nt], acc[mt][nt], 0, 0, 0);
        __syncthreads();
    }
#pragma unroll
    for (int nt = 0; nt < 4; nt++) {
        int n = n0 + wn * 64 + nt * 16 + l16;
        if (n >= 10000) continue;
        float bias = bout[n];
#pragma unroll
        for (int mt = 0; mt < 4; mt++) {
#pragma unroll
            for (int rr = 0; rr < 4; rr++) {
                int r = m0 + wm * 64 + mt * 16 + quad * 4 + rr;  // A row
                if (r < 4032) {
                    int s = (r >> 6) + 1, b = r & 63;
                    out[((long)b * 64 + s) * 10000 + n] = acc[mt][nt][rr] + bias;
                }
            }
        }
    }
}

extern "C" void kernel_launch(void* const* d_in, const int* in_sizes, int n_in,
                              void* d_out, int out_size, void* d_ws, size_t ws_size,
                              hipStream_t stream)
{
    const float* enc     = (const float*)d_in[0];
    const int*   targets = (const int*)d_in[1];
    const float* emb     = (const float*)d_in[2];
    const float* Wih     = (const float*)d_in[3];
    const float* Whh     = (const float*)d_in[4];
    const float* bih     = (const float*)d_in[5];
    const float* bhh     = (const float*)d_in[6];
    const float* Wh      = (const float*)d_in[7];
    const float* bh      = (const float*)d_in[8];
    const float* Wc      = (const float*)d_in[9];
    const float* bc      = (const float*)d_in[10];
    const float* Wout    = (const float*)d_in[11];
    const float* bout    = (const float*)d_in[12];
    float* out = (float*)d_out;

    char* ws = (char*)d_ws;
    size_t off = 0;
    auto alloc = [&](size_t bytes) {
        void* p = ws + off;
        off = (off + bytes + 255) & ~(size_t)255;
        return p;
    };
    unsigned short* mean_b = (unsigned short*)alloc((size_t)64 * 2048 * 2);
    unsigned short* Wih_b  = (unsigned short*)alloc((size_t)2048 * 512 * 2);
    unsigned short* Whh_b  = (unsigned short*)alloc((size_t)2048 * 512 * 2);
    unsigned short* Wh_b   = (unsigned short*)alloc((size_t)512 * 2048 * 2);
    unsigned short* Wc_b   = (unsigned short*)alloc((size_t)512 * 2048 * 2);
    unsigned short* Wout_b = (unsigned short*)alloc((size_t)10000 * 512 * 2);
    unsigned short* Aemb   = (unsigned short*)alloc((size_t)4032 * 512 * 2);
    float*          xg     = (float*)alloc((size_t)4032 * 2048 * 4);
    unsigned short* Hbuf   = (unsigned short*)alloc((size_t)64 * 64 * 512 * 2);
    float*          c0buf  = (float*)alloc((size_t)64 * 512 * 4);
    int*            ctrs   = (int*)alloc(256 * 4);
    float*          ps     = (float*)alloc((size_t)64 * 1024 * 4);

    k_prep<<<4096, 256, 0, stream>>>(Wih, Whh, Wh, Wc, Wout, emb, targets,
                                     Wih_b, Whh_b, Wh_b, Wc_b, Wout_b, Aemb, out, ctrs, ps);
    k_mean<<<dim3(16, 64), 128, 0, stream>>>(enc, mean_b);
    k_h0c0<<<dim3(16, 4), 256, 0, stream>>>(mean_b, Wh_b, Wc_b, ps);
    k_fin<<<256, 256, 0, stream>>>(ps, bh, bc, Hbuf, c0buf);
    k_xg<<<dim3(32, 63), 256, 0, stream>>>(Aemb, Wih_b, bih, bhh, xg);
    k_scan<<<64, 256, 0, stream>>>(Whh_b, xg, c0buf, Hbuf, ctrs);
    k_out<<<dim3(79, 32), 256, 0, stream>>>(Hbuf + 64 * 512, Wout_b, bout, out);
}